// Round 4
// baseline (76282.526 us; speedup 1.0000x reference)
//
#include <hip/hip_runtime.h>
#include <cstdint>

constexpr int B = 32, ET = 1024, DT = 1024, D = 256, PAD = 15, PT = ET + 2*PAD;
constexpr float LOG2E = 1.4426950408889634f;

// ws float layout
constexpr size_t PBUF_OFF = 0;                           // [B][2][PT] prev,cum (halo-padded)
constexpr size_t PART_OFF = PBUF_OFF + (size_t)B*2*PT;   // [B][16][D] att_out partials
constexpr size_t M_OFF    = PART_OFF + (size_t)B*16*D;   // [B][16] tile max
constexpr size_t S_OFF    = M_OFF + (size_t)B*16;        // [B][16] tile exp-sum
constexpr size_t WT_OFF   = S_OFF + (size_t)B*16;        // [62][D] transposed conv weights
constexpr size_t VSUM_OFF = WT_OFF + (size_t)62*D;       // scalar sum(v)
constexpr size_t CNT_OFF  = VSUM_OFF + 1;                // [B] uint barrier counters

__global__ __launch_bounds__(256) void k_init(const float* __restrict__ W,
                                              const float* __restrict__ v,
                                              float* __restrict__ ws) {
  int i0 = blockIdx.x*256 + threadIdx.x;
  int stride = gridDim.x*256;
  for (int i = i0; i < B*2*PT; i += stride) ws[PBUF_OFF + i] = 0.f;
  for (int i = i0; i < B*16*D; i += stride) ws[PART_OFF + i] = 0.f;
  for (int i = i0; i < 62*D; i += stride) {           // W_T[k][d] = W[d][k]
    int k = i >> 8, d = i & 255;
    ws[WT_OFF + i] = W[d*62 + k];
  }
  if (i0 < B) ((unsigned*)(ws + CNT_OFF))[i0] = 0u;
  if (i0 == 0) { float a = 0.f; for (int d = 0; d < D; ++d) a += v[d]; ws[VSUM_OFF] = a; }
}

template <int CTRL>
__device__ __forceinline__ float dpp_add(float x) {
  int y = __builtin_amdgcn_update_dpp(0, __float_as_int(x), CTRL, 0xF, 0xF, false);
  return x + __int_as_float(y);
}

// per-batch arrive-and-wait: 16 blocks, monotonic counter, agent scope
__device__ __forceinline__ void batch_barrier(unsigned* cnt, unsigned target, int tid) {
  __syncthreads();  // compiler drains vmcnt before s_barrier -> stores are in L2
  if (tid == 0) {
    __hip_atomic_fetch_add(cnt, 1u, __ATOMIC_RELEASE, __HIP_MEMORY_SCOPE_AGENT);
    while (__hip_atomic_load(cnt, __ATOMIC_ACQUIRE, __HIP_MEMORY_SCOPE_AGENT) < target)
      __builtin_amdgcn_s_sleep(1);
  }
  __syncthreads();
}

__global__ __launch_bounds__(256, 2) void k_decoder(
    const float* __restrict__ enc,   // [B][ET][D]
    const float* __restrict__ mel,   // [B][DT][D]
    const int* __restrict__ elen, const int* __restrict__ olen,
    const float* __restrict__ vw,    // [D]
    float* __restrict__ ws,
    float* __restrict__ out_att,     // [B][DT][D]
    float* __restrict__ out_sc) {    // [B][DT][ET]
  const int tid = threadIdx.x;
  const int lane = tid & 63, w = tid >> 6;
  const int bid = blockIdx.x;
  const int xcd = bid & 7, slot = bid >> 3;
  const int b = ((slot & 3) << 3) | xcd;   // 16 tile-blocks of b share an XCD (perf heuristic)
  const int tile = slot >> 2;              // 0..15
  const int t0 = tile * 64;

  float* pbuf = ws + PBUF_OFF + (size_t)b*2*PT;
  float* part = ws + PART_OFF + (size_t)b*16*D;
  float* Mb   = ws + M_OFF + b*16;
  float* Sb   = ws + S_OFF + b*16;
  const float* WT = ws + WT_OFF;
  unsigned* cnt = (unsigned*)(ws + CNT_OFF) + b;

  __shared__ float s_pa[96], s_pc[96], s_sc[64];
  __shared__ __align__(16) float s_part[64][20];

  // step-invariant residents
  float wr[62];
#pragma unroll
  for (int k = 0; k < 62; ++k) wr[k] = WT[k*D + tid];
  const float vd = vw[tid];
  const float vsum0 = ws[VSUM_OFF];
  const int L = elen[b];
  const int OL = olen[b];

  unsigned target = 0;
  for (int step = 0; step < DT; ++step) {
    // ---------------- phase 1: u, conv, energies, tile softmax stats ----------------
    if (tid < 96) {
      int ix = t0 + tid; if (ix > PT-1) ix = PT-1;
      s_pa[tid] = pbuf[ix];
      s_pc[tid] = pbuf[PT + ix];
    }
    float usum = 0.f;   // att_out(step-1), identical summation order in every block
    {
      const float* pp = part + tid;
#pragma unroll
      for (int j = 0; j < 16; ++j) usum += pp[j*D];
    }
    if (tile == 0 && step > 0) {
      float dmp = (step-1 < OL) ? 1.f : 0.f;
      out_att[((size_t)b*DT + step-1)*D + tid] = usum * dmp;
    }
    const float dm = (step < OL) ? 1.f : 0.f;
    const float ud = fmaf(mel[((size_t)b*DT + step)*D + tid], dm, usum);
    __syncthreads();

    float pa[32], pc[32];
#pragma unroll
    for (int k = 0; k < 31; ++k) { pa[k] = s_pa[k]; pc[k] = s_pc[k]; }

#pragma unroll 1
    for (int tb = 0; tb < 64; tb += 32) {
#pragma unroll
      for (int m = 0; m < 32; ++m) {
        const int tt = tb + m;
        float s0 = ud, s1 = 0.f, s2 = 0.f, s3 = 0.f;   // 4 chains hide FMA latency
#pragma unroll
        for (int k = 0; k < 15; ++k) {
          s0 = fmaf(wr[2*k],      pa[(m+2*k)&31],   s0);
          s1 = fmaf(wr[2*k+1],    pa[(m+2*k+1)&31], s1);
          s2 = fmaf(wr[31+2*k],   pc[(m+2*k)&31],   s2);
          s3 = fmaf(wr[31+2*k+1], pc[(m+2*k+1)&31], s3);
        }
        s0 = fmaf(wr[30], pa[(m+30)&31], s0);
        s2 = fmaf(wr[61], pc[(m+30)&31], s2);
        float s = (s0 + s1) + (s2 + s3);
        // sum_d v*tanh(s) = Vsum - 2*sum_d v/(exp(2s)+1)
        float ex = __builtin_amdgcn_exp2f(s * (2.f*LOG2E));
        float y  = vd * __builtin_amdgcn_rcpf(ex + 1.f);
        y = dpp_add<0xB1>(y);   // + lane^1
        y = dpp_add<0x4E>(y);   // + lane^2
        y = dpp_add<0x141>(y);  // row_half_mirror
        y = dpp_add<0x140>(y);  // row_mirror
        if ((lane & 15) == 0) s_part[tt][(w << 2) | (lane >> 4)] = y;
        pa[(m+31)&31] = s_pa[tt + 31];   // slide window (static idx under unroll)
        pc[(m+31)&31] = s_pc[tt + 31];
      }
    }
    __syncthreads();

    float e = 0.f;  // energy for t = t0+lane, lives in wave 0 across the barrier
    if (tid < 64) {
      const float4 r0 = *(const float4*)&s_part[tid][0];
      const float4 r1 = *(const float4*)&s_part[tid][4];
      const float4 r2 = *(const float4*)&s_part[tid][8];
      const float4 r3 = *(const float4*)&s_part[tid][12];
      float red = ((r0.x+r0.y)+(r0.z+r0.w)) + ((r1.x+r1.y)+(r1.z+r1.w))
                + ((r2.x+r2.y)+(r2.z+r2.w)) + ((r3.x+r3.y)+(r3.z+r3.w));
      e = vsum0 - 2.f*red;
      float tmax = e;
#pragma unroll
      for (int msk = 1; msk < 64; msk <<= 1) tmax = fmaxf(tmax, __shfl_xor(tmax, msk, 64));
      float te = __builtin_amdgcn_exp2f((e - tmax) * LOG2E);
#pragma unroll
      for (int msk = 1; msk < 64; msk <<= 1) te += __shfl_xor(te, msk, 64);
      if (lane == 0) { Mb[tile] = tmax; Sb[tile] = te; }
    }
    target += 16;
    batch_barrier(cnt, target, tid);

    // ---------------- phase 2: global softmax, state update, att partials ----------------
    if (tid < 64) {
      float mj = Mb[lane & 15], sj = Sb[lane & 15];
      float g = mj;
#pragma unroll
      for (int msk = 1; msk < 16; msk <<= 1) g = fmaxf(g, __shfl_xor(g, msk, 64));
      float z = sj * __builtin_amdgcn_exp2f((mj - g) * LOG2E);
#pragma unroll
      for (int msk = 1; msk < 16; msk <<= 1) z += __shfl_xor(z, msk, 64);
      float sc = __builtin_amdgcn_exp2f((e - g) * LOG2E) / z;
      int t = t0 + lane;
      if (t >= L) sc = 0.f;          // pad mask AFTER softmax (reference order)
      s_sc[lane] = sc;
      pbuf[PAD + t] = sc;            // prev score
      pbuf[PT + PAD + t] += sc;      // cumulative (this block is sole owner of slice)
      out_sc[((size_t)b*DT + step)*ET + t] = sc;
    }
    __syncthreads();

    {
      const float* eb = enc + ((size_t)b*ET + t0)*D + tid;
      float a0 = 0.f, a1 = 0.f, a2 = 0.f, a3 = 0.f;
      for (int r = 0; r < 64; r += 4) {
        a0 = fmaf(s_sc[r],   eb[(size_t)r*D],     a0);
        a1 = fmaf(s_sc[r+1], eb[(size_t)(r+1)*D], a1);
        a2 = fmaf(s_sc[r+2], eb[(size_t)(r+2)*D], a2);
        a3 = fmaf(s_sc[r+3], eb[(size_t)(r+3)*D], a3);
      }
      part[tile*D + tid] = (a0 + a1) + (a2 + a3);
    }
    target += 16;
    batch_barrier(cnt, target, tid);
  }

  // epilogue: out_att for the final step (all parts visible after last barrier)
  if (tile == 0) {
    float usum = 0.f;
    const float* pp = part + tid;
#pragma unroll
    for (int j = 0; j < 16; ++j) usum += pp[j*D];
    float dmp = (DT-1 < OL) ? 1.f : 0.f;
    out_att[((size_t)b*DT + DT-1)*D + tid] = usum * dmp;
  }
}

extern "C" void kernel_launch(void* const* d_in, const int* in_sizes, int n_in,
                              void* d_out, int out_size, void* d_ws, size_t ws_size,
                              hipStream_t stream) {
  const float* enc = (const float*)d_in[0];
  const float* mel = (const float*)d_in[1];
  const int* elen  = (const int*)d_in[2];
  const int* olen  = (const int*)d_in[3];
  const float* vw  = (const float*)d_in[4];   // [1, D]
  const float* W   = (const float*)d_in[5];   // [D, 2, KW]

  float* out_att = (float*)d_out;                 // [B, DT, D]
  float* out_sc  = out_att + (size_t)B*DT*D;      // [B, DT, ET]
  float* ws = (float*)d_ws;

  k_init<<<128, 256, 0, stream>>>(W, vw, ws);
  k_decoder<<<512, 256, 0, stream>>>(enc, mel, elen, olen, vw, ws, out_att, out_sc);
}

// Round 5
// 55447.150 us; speedup vs baseline: 1.3758x; 1.3758x over previous
//
#include <hip/hip_runtime.h>
#include <cstdint>

constexpr int B = 32, ET = 1024, DT = 1024, D = 256, PAD = 15, PT = ET + 2*PAD;
constexpr float LOG2E = 1.4426950408889634f;

// ws float layout
constexpr size_t PBUF_OFF = 0;                           // [B][2][PT] prev,cum (halo-padded)
constexpr size_t PART_OFF = PBUF_OFF + (size_t)B*2*PT;   // [B][16][D] att_out partials
constexpr size_t M_OFF    = PART_OFF + (size_t)B*16*D;   // [B][16] tile max
constexpr size_t S_OFF    = M_OFF + (size_t)B*16;        // [B][16] tile exp-sum
constexpr size_t WT_OFF   = S_OFF + (size_t)B*16;        // [62][D] transposed conv weights
constexpr size_t VSUM_OFF = WT_OFF + (size_t)62*D;       // scalar sum(v)
constexpr size_t CNT_OFF  = VSUM_OFF + 1;                // [B] uint barrier counters

__global__ __launch_bounds__(256) void k_init(const float* __restrict__ W,
                                              const float* __restrict__ v,
                                              float* __restrict__ ws) {
  int i0 = blockIdx.x*256 + threadIdx.x;
  int stride = gridDim.x*256;
  for (int i = i0; i < B*2*PT; i += stride) ws[PBUF_OFF + i] = 0.f;
  for (int i = i0; i < B*16*D; i += stride) ws[PART_OFF + i] = 0.f;
  for (int i = i0; i < 62*D; i += stride) {           // W_T[k][d] = W[d][k]
    int k = i >> 8, d = i & 255;
    ws[WT_OFF + i] = W[d*62 + k];
  }
  if (i0 < B) ((unsigned*)(ws + CNT_OFF))[i0] = 0u;
  if (i0 == 0) { float a = 0.f; for (int d = 0; d < D; ++d) a += v[d]; ws[VSUM_OFF] = a; }
}

template <int CTRL>
__device__ __forceinline__ float dpp_add(float x) {
  int y = __builtin_amdgcn_update_dpp(0, __float_as_int(x), CTRL, 0xF, 0xF, false);
  return x + __int_as_float(y);
}

// relaxed agent-scope accessors: sc-bit loads/stores that bypass L1/L2 to the
// coherence point -> cross-XCD coherent WITHOUT any wbl2/inv cache flushes.
__device__ __forceinline__ float aload(const float* p) {
  return __hip_atomic_load(p, __ATOMIC_RELAXED, __HIP_MEMORY_SCOPE_AGENT);
}
__device__ __forceinline__ void astore(float* p, float v) {
  __hip_atomic_store(p, v, __ATOMIC_RELAXED, __HIP_MEMORY_SCOPE_AGENT);
}

// per-batch arrive-and-wait, 16 blocks, monotonic counter, ZERO fences.
// hipcc drains vmcnt(0) before s_barrier, so all prior (coherence-point)
// stores are globally visible before the increment.
__device__ __forceinline__ void batch_barrier(unsigned* cnt, unsigned target, int tid) {
  __syncthreads();
  if (tid == 0) {
    __hip_atomic_fetch_add(cnt, 1u, __ATOMIC_RELAXED, __HIP_MEMORY_SCOPE_AGENT);
    while (__hip_atomic_load(cnt, __ATOMIC_RELAXED, __HIP_MEMORY_SCOPE_AGENT) < target)
      __builtin_amdgcn_s_sleep(2);
  }
  __syncthreads();
}

__global__ __attribute__((amdgpu_flat_work_group_size(256, 256), amdgpu_waves_per_eu(2, 2)))
void k_decoder(
    const float* __restrict__ enc,   // [B][ET][D]
    const float* __restrict__ mel,   // [B][DT][D]
    const int* __restrict__ elen, const int* __restrict__ olen,
    const float* __restrict__ vw,    // [D]
    float* __restrict__ ws,
    float* __restrict__ out_att,     // [B][DT][D]
    float* __restrict__ out_sc) {    // [B][DT][ET]
  const int tid = threadIdx.x;
  const int lane = tid & 63, w = tid >> 6;
  const int bid = blockIdx.x;
  const int xcd = bid & 7, slot = bid >> 3;
  const int b = ((slot & 3) << 3) | xcd;   // perf heuristic only (L2 locality)
  const int tile = slot >> 2;              // 0..15
  const int t0 = tile * 64;

  float* pbuf = ws + PBUF_OFF + (size_t)b*2*PT;
  float* part = ws + PART_OFF + (size_t)b*16*D;
  float* Mb   = ws + M_OFF + b*16;
  float* Sb   = ws + S_OFF + b*16;
  const float* WT = ws + WT_OFF;
  unsigned* cnt = (unsigned*)(ws + CNT_OFF) + b;

  __shared__ float s_pa[96], s_pc[96], s_sc[64];
  __shared__ __align__(16) float s_part[64][20];

  // step-invariant residents
  float wr[62];
#pragma unroll
  for (int k = 0; k < 62; ++k) wr[k] = WT[k*D + tid];
  const float vd = vw[tid];
  const float vsum0 = ws[VSUM_OFF];
  const int L = elen[b];
  const int OL = olen[b];

  unsigned target = 0;
#pragma unroll 1
  for (int step = 0; step < DT; ++step) {
    // -------- phase 1: u, conv, energies, tile softmax stats --------
    float usum = 0.f;   // att_out(step-1): same summation order in every block
    {
      const float* pp = part + tid;
#pragma unroll
      for (int j = 0; j < 16; ++j) usum += aload(pp + j*D);
    }
    if (tid < 96) {
      int ix = t0 + tid; if (ix > PT-1) ix = PT-1;
      s_pa[tid] = aload(pbuf + ix);
      s_pc[tid] = aload(pbuf + PT + ix);
    }
    if (tile == 0 && step > 0) {
      float dmp = (step-1 < OL) ? 1.f : 0.f;
      out_att[((size_t)b*DT + step-1)*D + tid] = usum * dmp;
    }
    const float dm = (step < OL) ? 1.f : 0.f;
    const float ud = fmaf(mel[((size_t)b*DT + step)*D + tid], dm, usum);
    __syncthreads();

    float pa[32], pc[32];
#pragma unroll
    for (int k = 0; k < 31; ++k) { pa[k] = s_pa[k]; pc[k] = s_pc[k]; }

#pragma unroll 1
    for (int tb = 0; tb < 64; tb += 32) {
#pragma unroll
      for (int m = 0; m < 32; ++m) {
        const int tt = tb + m;
        float s0 = ud, s1 = 0.f, s2 = 0.f, s3 = 0.f;   // 4 chains hide FMA latency
#pragma unroll
        for (int k = 0; k < 15; ++k) {
          s0 = fmaf(wr[2*k],      pa[(m+2*k)&31],   s0);
          s1 = fmaf(wr[2*k+1],    pa[(m+2*k+1)&31], s1);
          s2 = fmaf(wr[31+2*k],   pc[(m+2*k)&31],   s2);
          s3 = fmaf(wr[31+2*k+1], pc[(m+2*k+1)&31], s3);
        }
        s0 = fmaf(wr[30], pa[(m+30)&31], s0);
        s2 = fmaf(wr[61], pc[(m+30)&31], s2);
        float s = (s0 + s1) + (s2 + s3);
        // sum_d v*tanh(s) = Vsum - 2*sum_d v/(exp(2s)+1)
        float ex = __builtin_amdgcn_exp2f(s * (2.f*LOG2E));
        float y  = vd * __builtin_amdgcn_rcpf(ex + 1.f);
        y = dpp_add<0xB1>(y);   // + lane^1
        y = dpp_add<0x4E>(y);   // + lane^2
        y = dpp_add<0x141>(y);  // row_half_mirror
        y = dpp_add<0x140>(y);  // row_mirror
        if ((lane & 15) == 0) s_part[tt][(w << 2) | (lane >> 4)] = y;
        pa[(m+31)&31] = s_pa[tt + 31];   // slide window (static idx under unroll)
        pc[(m+31)&31] = s_pc[tt + 31];
      }
    }
    __syncthreads();

    float e = 0.f;  // energy for t = t0+lane, stays in wave-0 regs across barrier
    if (tid < 64) {
      const float4 r0 = *(const float4*)&s_part[tid][0];
      const float4 r1 = *(const float4*)&s_part[tid][4];
      const float4 r2 = *(const float4*)&s_part[tid][8];
      const float4 r3 = *(const float4*)&s_part[tid][12];
      float red = ((r0.x+r0.y)+(r0.z+r0.w)) + ((r1.x+r1.y)+(r1.z+r1.w))
                + ((r2.x+r2.y)+(r2.z+r2.w)) + ((r3.x+r3.y)+(r3.z+r3.w));
      e = vsum0 - 2.f*red;
      float tmax = e;
#pragma unroll
      for (int msk = 1; msk < 64; msk <<= 1) tmax = fmaxf(tmax, __shfl_xor(tmax, msk, 64));
      float te = __builtin_amdgcn_exp2f((e - tmax) * LOG2E);
#pragma unroll
      for (int msk = 1; msk < 64; msk <<= 1) te += __shfl_xor(te, msk, 64);
      if (lane == 0) { astore(Mb + tile, tmax); astore(Sb + tile, te); }
    }
    target += 16;
    batch_barrier(cnt, target, tid);

    // -------- phase 2: global softmax, state update, att partials --------
    if (tid < 64) {
      float mj = aload(Mb + (lane & 15)), sj = aload(Sb + (lane & 15));
      float g = mj;
#pragma unroll
      for (int msk = 1; msk < 16; msk <<= 1) g = fmaxf(g, __shfl_xor(g, msk, 64));
      float z = sj * __builtin_amdgcn_exp2f((mj - g) * LOG2E);
#pragma unroll
      for (int msk = 1; msk < 16; msk <<= 1) z += __shfl_xor(z, msk, 64);
      float sc = __builtin_amdgcn_exp2f((e - g) * LOG2E) / z;
      int t = t0 + lane;
      if (t >= L) sc = 0.f;          // pad mask AFTER softmax (reference order)
      s_sc[lane] = sc;
      astore(pbuf + PAD + t, sc);                       // prev score
      float c = aload(pbuf + PT + PAD + t);             // cumulative (sole owner)
      astore(pbuf + PT + PAD + t, c + sc);
      out_sc[((size_t)b*DT + step)*ET + t] = sc;
    }
    __syncthreads();

    if (t0 < L) {   // tiles fully beyond elen contribute part==0 (set by k_init)
      const float* eb = enc + ((size_t)b*ET + t0)*D + tid;
      float a0 = 0.f, a1 = 0.f, a2 = 0.f, a3 = 0.f;
      for (int r = 0; r < 64; r += 4) {
        a0 = fmaf(s_sc[r],   eb[(size_t)r*D],     a0);
        a1 = fmaf(s_sc[r+1], eb[(size_t)(r+1)*D], a1);
        a2 = fmaf(s_sc[r+2], eb[(size_t)(r+2)*D], a2);
        a3 = fmaf(s_sc[r+3], eb[(size_t)(r+3)*D], a3);
      }
      astore(part + tile*D + tid, (a0 + a1) + (a2 + a3));
    }
    target += 16;
    batch_barrier(cnt, target, tid);
  }

  // epilogue: out_att for the final step
  if (tile == 0) {
    float usum = 0.f;
    const float* pp = part + tid;
#pragma unroll
    for (int j = 0; j < 16; ++j) usum += aload(pp + j*D);
    float dmp = (DT-1 < OL) ? 1.f : 0.f;
    out_att[((size_t)b*DT + DT-1)*D + tid] = usum * dmp;
  }
}

extern "C" void kernel_launch(void* const* d_in, const int* in_sizes, int n_in,
                              void* d_out, int out_size, void* d_ws, size_t ws_size,
                              hipStream_t stream) {
  const float* enc = (const float*)d_in[0];
  const float* mel = (const float*)d_in[1];
  const int* elen  = (const int*)d_in[2];
  const int* olen  = (const int*)d_in[3];
  const float* vw  = (const float*)d_in[4];   // [1, D]
  const float* W   = (const float*)d_in[5];   // [D, 2, KW]

  float* out_att = (float*)d_out;                 // [B, DT, D]
  float* out_sc  = out_att + (size_t)B*DT*D;      // [B, DT, ET]
  float* ws = (float*)d_ws;

  k_init<<<128, 256, 0, stream>>>(W, vw, ws);
  k_decoder<<<512, 256, 0, stream>>>(enc, mel, elen, olen, vw, ws, out_att, out_sc);
}